// Round 2
// baseline (603.402 us; speedup 1.0000x reference)
//
#include <hip/hip_runtime.h>

// Problem constants (match reference setup_inputs)
constexpr int B = 64, H = 128, E = 128, NL = 4, S = 8192, V = 50257;

// ================= Kernel A: embed + 4x LSTM + fold Wq/Wk into q =================
// 64 blocks (1 per batch) x 512 threads (1 per gate column). Layers chained in LDS.
__global__ __launch_bounds__(512) void k_lstm_stack(const int* __restrict__ tok,
    const float* __restrict__ emb, const float* __restrict__ c0,
    const float* __restrict__ h0, const float* __restrict__ Wi_all,
    const float* __restrict__ Uh_all, const float* __restrict__ b_all,
    const float* __restrict__ Wq, const float* __restrict__ bq,
    const float* __restrict__ Wk, const float* __restrict__ bk,
    float* __restrict__ out_c, float* __restrict__ out_h,
    float* __restrict__ xf, float* __restrict__ qk, float* __restrict__ qc) {
    int b = blockIdx.x, g = threadIdx.x;
    __shared__ float xs[128], hs[128], gl[512], qs[128], ps[128];
    if (g < 128) xs[g] = emb[(long)tok[b] * E + g];

    for (int l = 0; l < NL; ++l) {
        if (g < 128) hs[g] = h0[(l * B + b) * H + g];
        __syncthreads();                       // xs & hs ready for this layer
        const float* Wi = Wi_all + l * (E * 4 * H);
        const float* Uh = Uh_all + l * (H * 4 * H);
        float a0 = 0.f, a1 = 0.f, a2 = 0.f, a3 = 0.f;
        #pragma unroll 8
        for (int e = 0; e < 128; e += 4) {
            a0 += xs[e]     * Wi[(e)     * 512 + g];
            a1 += xs[e + 1] * Wi[(e + 1) * 512 + g];
            a2 += xs[e + 2] * Wi[(e + 2) * 512 + g];
            a3 += xs[e + 3] * Wi[(e + 3) * 512 + g];
        }
        #pragma unroll 8
        for (int e = 0; e < 128; e += 4) {
            a0 += hs[e]     * Uh[(e)     * 512 + g];
            a1 += hs[e + 1] * Uh[(e + 1) * 512 + g];
            a2 += hs[e + 2] * Uh[(e + 2) * 512 + g];
            a3 += hs[e + 3] * Uh[(e + 3) * 512 + g];
        }
        gl[g] = (a0 + a1) + (a2 + a3) + b_all[l * 512 + g];
        __syncthreads();                       // gates ready; xs/hs reads done
        if (g < 128) {
            float i_g = gl[g], f_g = gl[128 + g], g_g = gl[256 + g], o_g = gl[384 + g];
            float si = 1.f / (1.f + expf(-i_g));
            float sf = 1.f / (1.f + expf(-f_g));
            float so = 1.f / (1.f + expf(-o_g));
            float c = sf * c0[(l * B + b) * H + g] + si * tanhf(g_g);
            float hh = so * tanhf(c);
            out_c[(l * B + b) * H + g] = c;
            out_h[(l * B + b) * H + g] = hh;
            xs[g] = hh;                        // safe: all xs reads completed at last sync
        }
    }
    __syncthreads();                           // final x visible to all

    // tail: xf, q = x@Wq+bq, qk = (1/sqrt(H)) * Wk @ q, qc = (1/sqrt(H)) * bk.q
    if (g < 128) {
        xf[b * H + g] = xs[g];
        float q = bq[g];
        for (int h = 0; h < 128; ++h) q += xs[h] * Wq[h * 128 + g];
        qs[g] = q;
        ps[g] = q * bk[g];
    }
    __syncthreads();
    const float inv = 0.08838834764831845f;    // 1/sqrt(128)
    if (g < 128) {
        float acc = 0.f;
        for (int i = 0; i < 128; ++i) acc += Wk[g * 128 + i] * qs[i];
        qk[b * H + g] = acc * inv;
    }
    if (g == 0) {
        float s = 0.f;
        for (int i = 0; i < 128; ++i) s += ps[i];
        qc[b] = s * inv;
    }
}

// ================= Kernel B: copy mem->out + scores + split-softmax partials ======
// One block per (b, chunk of 64 rows). 256 thr = 8 half-waves; half-wave hw owns rows
// hw+8k (k=0..7), lane l32 holds float4 h-slice [l32*4 .. l32*4+3]. Rows stay in regs:
// copy, score (shfl-reduce), chunk max/denom, weighted u-partial -- one HBM pass.
__global__ __launch_bounds__(256) void k_copy_fuse(const float* __restrict__ mem,
    const float* __restrict__ xf, const float* __restrict__ qk,
    const float* __restrict__ qc, const int* __restrict__ stepp,
    float* __restrict__ out_mem, float* __restrict__ part) {
    int step = *stepp;
    int bc = blockIdx.x;                 // [0, B * S/64)
    int b = bc >> 7;                     // S/64 = 128 chunks per batch
    int chunk = bc & 127;
    int s0 = chunk << 6;
    int t = threadIdx.x;
    int wave = t >> 6, lane = t & 63, half = lane >> 5, l32 = lane & 31;
    int hw = wave * 2 + half;            // 0..7
    long base = ((long)b << 13) + s0;    // global row index of chunk start

    __shared__ float sc_lds[64];
    __shared__ float wts[64];
    __shared__ float upart[8][128];
    __shared__ float mred[2];

    bool active = (s0 <= step);
    float4 qv = active ? ((const float4*)(qk + b * H))[l32] : float4{0, 0, 0, 0};
    float qcb = active ? qc[b] : 0.f;

    float4 v[8];
    #pragma unroll
    for (int k = 0; k < 8; ++k) {
        int r = hw + 8 * k;
        int s = s0 + r;
        const float4* src = (s == step) ? (const float4*)(xf + b * H)
                                        : (const float4*)(mem + (base + r) * H);
        v[k] = src[l32];
        ((float4*)(out_mem + (base + r) * H))[l32] = v[k];
    }
    if (!active) return;                 // block-uniform; no syncs crossed

    #pragma unroll
    for (int k = 0; k < 8; ++k) {
        int r = hw + 8 * k;
        int s = s0 + r;
        float p = v[k].x * qv.x + v[k].y * qv.y + v[k].z * qv.z + v[k].w * qv.w;
        p += __shfl_xor(p, 16); p += __shfl_xor(p, 8); p += __shfl_xor(p, 4);
        p += __shfl_xor(p, 2);  p += __shfl_xor(p, 1);
        if (l32 == 0) sc_lds[r] = (s <= step) ? (p + qcb) : -1e30f;
    }
    __syncthreads();
    if (t < 64) {                        // wave 0: chunk max, weights, denom partial
        float sc = sc_lds[t];
        float m = sc;
        for (int msk = 32; msk; msk >>= 1) m = fmaxf(m, __shfl_xor(m, msk));
        float e = expf(sc - m);          // masked rows: exp(-1e30 - m) -> 0
        wts[t] = e;
        float d = e;
        for (int msk = 32; msk; msk >>= 1) d += __shfl_xor(d, msk);
        if (t == 0) { mred[0] = m; mred[1] = d; }
    }
    __syncthreads();
    float4 ua = {0, 0, 0, 0};
    #pragma unroll
    for (int k = 0; k < 8; ++k) {
        float w = wts[hw + 8 * k];
        ua.x += w * v[k].x; ua.y += w * v[k].y; ua.z += w * v[k].z; ua.w += w * v[k].w;
    }
    ((float4*)&upart[hw][0])[l32] = ua;
    __syncthreads();
    float* prec = part + (long)bc * 132;
    if (t < 128) {
        float s = 0.f;
        #pragma unroll
        for (int w2 = 0; w2 < 8; ++w2) s += upart[w2][t];
        prec[2 + t] = s;
    }
    if (t == 0) { prec[0] = mred[0]; prec[1] = mred[1]; }
}

// ================= Kernel C: softmax combine + ctx=u@Wv+bv + mix + LayerNorm ======
// 64 blocks (1/batch) x 128 threads. Writes h_ln transposed [h][b] for k_logits.
__global__ __launch_bounds__(128) void k_combine_mix(const float* __restrict__ part,
    const int* __restrict__ stepp, const float* __restrict__ xf,
    const float* __restrict__ Wv, const float* __restrict__ bv,
    const float* __restrict__ Wmix, const float* __restrict__ bmix,
    const float* __restrict__ lns, const float* __restrict__ lnb,
    float* __restrict__ hlnT) {
    int b = blockIdx.x, j = threadIdx.x;
    int nc = (*stepp >> 6) + 1;          // active chunks per batch (<= 128)
    __shared__ float mcs[128], scl[128], red[128], ul[128], cl[128], xl[128];
    float mc = -1e30f, dc = 0.f;
    if (j < nc) {
        const float* pr = part + (long)(b * 128 + j) * 132;
        mc = pr[0]; dc = pr[1];
    }
    mcs[j] = mc;
    __syncthreads();
    for (int o = 64; o; o >>= 1) { if (j < o) mcs[j] = fmaxf(mcs[j], mcs[j + o]); __syncthreads(); }
    float m = mcs[0];
    float e = (j < nc) ? expf(mc - m) : 0.f;
    scl[j] = e;
    red[j] = dc * e;
    __syncthreads();
    for (int o = 64; o; o >>= 1) { if (j < o) red[j] += red[j + o]; __syncthreads(); }
    float rden = 1.f / red[0];
    float u = 0.f;
    for (int c = 0; c < nc; ++c)
        u += part[(long)(b * 128 + c) * 132 + 2 + j] * scl[c];
    u *= rden;
    ul[j] = u;
    xl[j] = xf[b * H + j];
    __syncthreads();
    float cv = bv[j];                    // ctx = u@Wv + bv  (sum of weights == 1)
    for (int i = 0; i < 128; ++i) cv += ul[i] * Wv[i * 128 + j];
    cl[j] = cv;
    __syncthreads();
    float hm = bmix[j];
    for (int i = 0; i < 128; ++i) hm += xl[i] * Wmix[i * 128 + j];
    for (int i = 0; i < 128; ++i) hm += cl[i] * Wmix[(128 + i) * 128 + j];
    hm = tanhf(hm);
    red[j] = hm; __syncthreads();
    for (int o = 64; o; o >>= 1) { if (j < o) red[j] += red[j + o]; __syncthreads(); }
    float mu = red[0] * (1.f / 128.f); __syncthreads();
    float d = hm - mu;
    red[j] = d * d; __syncthreads();
    for (int o = 64; o; o >>= 1) { if (j < o) red[j] += red[j + o]; __syncthreads(); }
    float var = red[0] * (1.f / 128.f);
    hlnT[j * B + b] = d * rsqrtf(var + 1e-6f) * lns[j] + lnb[j];
}

// ================= Kernel D: logits = h_ln @ Wout + bout =================
// 256 thr = 64 v-lanes x 4 b-groups (16 b each); hlnT staged in LDS (32 KiB).
__global__ __launch_bounds__(256) void k_logits(const float* __restrict__ hlnT,
    const float* __restrict__ Wout, const float* __restrict__ bout,
    float* __restrict__ logits) {
    __shared__ float hl[H * B];
    int t = threadIdx.x;
    for (int i = t; i < H * B; i += 256) hl[i] = hlnT[i];
    __syncthreads();
    int vi = t & 63, bg = t >> 6;
    int v = blockIdx.x * 64 + vi;
    if (v >= V) return;
    float acc[16];
    #pragma unroll
    for (int i = 0; i < 16; ++i) acc[i] = 0.f;
    const float4* hl4 = (const float4*)hl;
    #pragma unroll 4
    for (int h = 0; h < 128; ++h) {
        float wv = Wout[(long)h * V + v];
        float4 a0 = hl4[h * 16 + bg * 4 + 0];
        float4 a1 = hl4[h * 16 + bg * 4 + 1];
        float4 a2 = hl4[h * 16 + bg * 4 + 2];
        float4 a3 = hl4[h * 16 + bg * 4 + 3];
        acc[0]  += a0.x * wv; acc[1]  += a0.y * wv; acc[2]  += a0.z * wv; acc[3]  += a0.w * wv;
        acc[4]  += a1.x * wv; acc[5]  += a1.y * wv; acc[6]  += a1.z * wv; acc[7]  += a1.w * wv;
        acc[8]  += a2.x * wv; acc[9]  += a2.y * wv; acc[10] += a2.z * wv; acc[11] += a2.w * wv;
        acc[12] += a3.x * wv; acc[13] += a3.y * wv; acc[14] += a3.z * wv; acc[15] += a3.w * wv;
    }
    float bo = bout[v];
    #pragma unroll
    for (int bb = 0; bb < 16; ++bb)
        logits[(long)(bg * 16 + bb) * V + v] = acc[bb] + bo;
}

extern "C" void kernel_launch(void* const* d_in, const int* in_sizes, int n_in,
                              void* d_out, int out_size, void* d_ws, size_t ws_size,
                              hipStream_t stream) {
    const int*   tok   = (const int*)d_in[0];
    const float* c0    = (const float*)d_in[1];
    const float* h0    = (const float*)d_in[2];
    const float* mem   = (const float*)d_in[3];
    const int*   stepp = (const int*)d_in[4];
    const float* emb   = (const float*)d_in[5];
    const float* Wi    = (const float*)d_in[6];
    const float* Uh    = (const float*)d_in[7];
    const float* lb    = (const float*)d_in[8];
    const float* Wq    = (const float*)d_in[9];
    const float* bq    = (const float*)d_in[10];
    const float* Wk    = (const float*)d_in[11];
    const float* bk    = (const float*)d_in[12];
    const float* Wv    = (const float*)d_in[13];
    const float* bv    = (const float*)d_in[14];
    const float* Wmix  = (const float*)d_in[15];
    const float* bmix  = (const float*)d_in[16];
    const float* lns   = (const float*)d_in[17];
    const float* lnb   = (const float*)d_in[18];
    const float* Wout  = (const float*)d_in[19];
    const float* bout  = (const float*)d_in[20];

    float* out     = (float*)d_out;
    float* logits  = out;                       // [B,V] = 3216448 floats
    float* out_c   = out + 3216448;             // [L,B,H]
    float* out_h   = out_c + 32768;             // [L,B,H]
    float* out_mem = out_h + 32768;             // [B,S,H]

    // workspace layout (floats)
    float* ws   = (float*)d_ws;
    float* xf   = ws;            // 8192
    float* qk   = ws + 8192;     // 8192
    float* qc   = ws + 16384;    // 64
    float* hlnT = ws + 16448;    // 8192
    // partials: B * 128 chunks * 132 floats = 1081344 (~4.3 MB)
    size_t need = (size_t)(24640 + B * 128 * 132) * sizeof(float);
    float* part = (ws_size >= need) ? (ws + 24640) : logits;  // logits written last

    k_lstm_stack<<<B, 512, 0, stream>>>(tok, emb, c0, h0, Wi, Uh, lb,
                                        Wq, bq, Wk, bk, out_c, out_h, xf, qk, qc);
    k_copy_fuse<<<B * (S / 64), 256, 0, stream>>>(mem, xf, qk, qc, stepp, out_mem, part);
    k_combine_mix<<<B, 128, 0, stream>>>(part, stepp, xf, Wv, bv, Wmix, bmix,
                                         lns, lnb, hlnT);
    k_logits<<<(V + 63) / 64, 256, 0, stream>>>(hlnT, Wout, bout, logits);
}